// Round 1
// baseline (1009.065 us; speedup 1.0000x reference)
//
#include <hip/hip_runtime.h>

typedef __attribute__((ext_vector_type(8))) short s16x8;
typedef __attribute__((ext_vector_type(8))) unsigned short u16x8;
typedef __attribute__((ext_vector_type(4))) float f32x4;

#define LN_EPS 1e-5f

__device__ __forceinline__ unsigned short f2bf(float f) {
  unsigned int u = __float_as_uint(f);
  u += 0x7fffu + ((u >> 16) & 1u);
  return (unsigned short)(u >> 16);
}

__device__ __forceinline__ float gelu_exact(float x) {
  return 0.5f * x * (1.0f + erff(x * 0.70710678118654752f));
}

// ws layout (ushort elems):
//   [0, 65536)        Wt1[n=256][k=256]  (= W1^T, bf16)
//   [65536, 98304)    Wt2[n=128][k=256]  (= W2^T, bf16)
//   [98304, 114688)   Wtm[n=128][k=128]  (= Wm[0:128]^T, bf16)
//   ushort off 114688: 128 f32 = Wm[128, :] (importance row, kept f32)
__global__ void prep_weights(const float* __restrict__ W1, const float* __restrict__ W2,
                             const float* __restrict__ Wm, unsigned short* __restrict__ ws) {
  int i = blockIdx.x * 256 + threadIdx.x;
  if (i < 65536) {
    int n = i >> 8, k = i & 255;
    ws[i] = f2bf(W1[k * 256 + n]);
  } else if (i < 98304) {
    int j = i - 65536; int n = j >> 8, k = j & 255;
    ws[i] = f2bf(W2[k * 128 + n]);
  } else if (i < 114688) {
    int j = i - 98304; int n = j >> 7, k = j & 127;
    ws[i] = f2bf(Wm[k * 128 + n]);
  } else if (i < 114816) {
    int c = i - 114688;
    reinterpret_cast<float*>(ws + 114688)[c] = Wm[128 * 128 + c];
  }
}

__global__ __launch_bounds__(256, 2) void fused_edge_group(
    const float* __restrict__ emb, const int* __restrict__ eg,
    const float* __restrict__ imp,
    const float* __restrict__ b1, const float* __restrict__ g1, const float* __restrict__ be1,
    const float* __restrict__ b2, const float* __restrict__ g2, const float* __restrict__ be2,
    const float* __restrict__ bm,
    const unsigned short* __restrict__ ws,
    float* __restrict__ out, int G) {

  // 64 groups per block; bf16 tiles, XOR-swizzled (byte ^= (row&7)<<4) to kill
  // the row-major 512B/256B-stride bank conflicts on ds_read_b128.
  __shared__ __align__(16) unsigned short lds_X[64 * 256];   // concat  32KB
  __shared__ __align__(16) unsigned short lds_H1[64 * 256];  // LN1 out 32KB
  __shared__ __align__(16) unsigned short lds_H2[64 * 128];  // LN2 out 16KB

  const int tid = threadIdx.x;
  const int g0 = blockIdx.x * 64;

  // ---- gather: 64 rows x 2 halves x 512B, convert to bf16 into lds_X ----
  #pragma unroll
  for (int it = 0; it < 8; ++it) {
    int s = tid + it * 256;      // 0..2047 : 16B slots of [64][512B]
    int row = s >> 5;
    int sc = s & 31;             // 16B slot within row
    int half = sc >> 4;
    int f0 = (sc & 15) * 8;      // float offset within the 128-float half
    int g = g0 + row; if (g >= G) g = G - 1;
    int idx = eg[g * 2 + half];
    const float4* src = reinterpret_cast<const float4*>(emb + (size_t)idx * 128 + f0);
    float4 va = src[0], vb = src[1];
    u16x8 v;
    v[0] = f2bf(va.x); v[1] = f2bf(va.y); v[2] = f2bf(va.z); v[3] = f2bf(va.w);
    v[4] = f2bf(vb.x); v[5] = f2bf(vb.y); v[6] = f2bf(vb.z); v[7] = f2bf(vb.w);
    int byte = (row * 512 + sc * 16) ^ ((row & 7) << 4);
    *reinterpret_cast<u16x8*>(reinterpret_cast<char*>(lds_X) + byte) = v;
  }
  __syncthreads();

  const int lane = tid & 63;
  const int wave = tid >> 6;     // 4 waves, M-split: wave owns rows [wave*16, +16)
  const int l15 = lane & 15;
  const int lgrp = lane >> 4;    // 0..3
  const int arow = wave * 16 + l15;          // A-fragment row (block-local)
  const int aswz = (arow & 7) << 4;

  const unsigned short* wt1 = ws;
  const unsigned short* wt2 = ws + 65536;
  const unsigned short* wtm = ws + 98304;
  const float* wml = reinterpret_cast<const float*>(ws + 114688);

  // ---- GEMM1: [16 x 256] = X[16 x 256k] * W1[256k x 256n] ----
  f32x4 acc1[16];
  #pragma unroll
  for (int nf = 0; nf < 16; ++nf) acc1[nf] = (f32x4){0.f, 0.f, 0.f, 0.f};
  for (int kk = 0; kk < 8; ++kk) {
    int abyte = (arow * 512 + kk * 64 + lgrp * 16) ^ aswz;
    s16x8 af = *reinterpret_cast<const s16x8*>(reinterpret_cast<const char*>(lds_X) + abyte);
    #pragma unroll
    for (int nf = 0; nf < 16; ++nf) {
      int n = nf * 16 + l15;
      s16x8 bf = *reinterpret_cast<const s16x8*>(wt1 + n * 256 + kk * 32 + lgrp * 8);
      acc1[nf] = __builtin_amdgcn_mfma_f32_16x16x32_bf16(af, bf, acc1[nf], 0, 0, 0);
    }
  }

  // ---- epilogue 1: +b1, exact GELU, LayerNorm -> lds_H1 (bf16) ----
  {
    float s[4] = {0, 0, 0, 0}, q[4] = {0, 0, 0, 0};
    #pragma unroll
    for (int nf = 0; nf < 16; ++nf) {
      float bb = b1[nf * 16 + l15];
      #pragma unroll
      for (int r = 0; r < 4; ++r) {
        float x = acc1[nf][r] + bb;
        x = gelu_exact(x);
        acc1[nf][r] = x;
        s[r] += x; q[r] += x * x;
      }
    }
    #pragma unroll
    for (int m = 1; m < 16; m <<= 1) {
      #pragma unroll
      for (int r = 0; r < 4; ++r) { s[r] += __shfl_xor(s[r], m); q[r] += __shfl_xor(q[r], m); }
    }
    float mu[4], rs[4];
    #pragma unroll
    for (int r = 0; r < 4; ++r) {
      mu[r] = s[r] * (1.f / 256.f);
      float var = q[r] * (1.f / 256.f) - mu[r] * mu[r];
      rs[r] = rsqrtf(var + LN_EPS);
    }
    #pragma unroll
    for (int nf = 0; nf < 16; ++nf) {
      int col = nf * 16 + l15;
      float gam = g1[col], bet = be1[col];
      #pragma unroll
      for (int r = 0; r < 4; ++r) {
        float y = (acc1[nf][r] - mu[r]) * rs[r] * gam + bet;
        int row = wave * 16 + lgrp * 4 + r;
        int byte = (row * 512 + col * 2) ^ ((row & 7) << 4);
        *reinterpret_cast<unsigned short*>(reinterpret_cast<char*>(lds_H1) + byte) = f2bf(y);
      }
    }
  }
  __syncthreads();

  // ---- GEMM2: [16 x 128] = H1[16 x 256k] * W2[256k x 128n] ----
  f32x4 acc2[8];
  #pragma unroll
  for (int nf = 0; nf < 8; ++nf) acc2[nf] = (f32x4){0.f, 0.f, 0.f, 0.f};
  for (int kk = 0; kk < 8; ++kk) {
    int abyte = (arow * 512 + kk * 64 + lgrp * 16) ^ aswz;
    s16x8 af = *reinterpret_cast<const s16x8*>(reinterpret_cast<const char*>(lds_H1) + abyte);
    #pragma unroll
    for (int nf = 0; nf < 8; ++nf) {
      int n = nf * 16 + l15;
      s16x8 bf = *reinterpret_cast<const s16x8*>(wt2 + n * 256 + kk * 32 + lgrp * 8);
      acc2[nf] = __builtin_amdgcn_mfma_f32_16x16x32_bf16(af, bf, acc2[nf], 0, 0, 0);
    }
  }

  // ---- epilogue 2: +b2, ReLU, LayerNorm -> lds_H2 (bf16) ----
  {
    float s[4] = {0, 0, 0, 0}, q[4] = {0, 0, 0, 0};
    #pragma unroll
    for (int nf = 0; nf < 8; ++nf) {
      float bb = b2[nf * 16 + l15];
      #pragma unroll
      for (int r = 0; r < 4; ++r) {
        float x = fmaxf(acc2[nf][r] + bb, 0.f);
        acc2[nf][r] = x;
        s[r] += x; q[r] += x * x;
      }
    }
    #pragma unroll
    for (int m = 1; m < 16; m <<= 1) {
      #pragma unroll
      for (int r = 0; r < 4; ++r) { s[r] += __shfl_xor(s[r], m); q[r] += __shfl_xor(q[r], m); }
    }
    float mu[4], rs[4];
    #pragma unroll
    for (int r = 0; r < 4; ++r) {
      mu[r] = s[r] * (1.f / 128.f);
      float var = q[r] * (1.f / 128.f) - mu[r] * mu[r];
      rs[r] = rsqrtf(var + LN_EPS);
    }
    #pragma unroll
    for (int nf = 0; nf < 8; ++nf) {
      int col = nf * 16 + l15;
      float gam = g2[col], bet = be2[col];
      #pragma unroll
      for (int r = 0; r < 4; ++r) {
        float y = (acc2[nf][r] - mu[r]) * rs[r] * gam + bet;
        int row = wave * 16 + lgrp * 4 + r;
        int byte = (row * 256 + col * 2) ^ ((row & 7) << 4);
        *reinterpret_cast<unsigned short*>(reinterpret_cast<char*>(lds_H2) + byte) = f2bf(y);
      }
    }
  }
  __syncthreads();

  // ---- GEMM3: [16 x 128] = H2[16 x 128k] * Wm[0:128][128n] ----
  f32x4 acc3[8];
  #pragma unroll
  for (int nf = 0; nf < 8; ++nf) acc3[nf] = (f32x4){0.f, 0.f, 0.f, 0.f};
  for (int kk = 0; kk < 4; ++kk) {
    int abyte = (arow * 256 + kk * 64 + lgrp * 16) ^ aswz;
    s16x8 af = *reinterpret_cast<const s16x8*>(reinterpret_cast<const char*>(lds_H2) + abyte);
    #pragma unroll
    for (int nf = 0; nf < 8; ++nf) {
      int n = nf * 16 + l15;
      s16x8 bf = *reinterpret_cast<const s16x8*>(wtm + n * 128 + kk * 32 + lgrp * 8);
      acc3[nf] = __builtin_amdgcn_mfma_f32_16x16x32_bf16(af, bf, acc3[nf], 0, 0, 0);
    }
  }

  // ---- epilogue 3: + bm + imp * Wm[128,:], ReLU, store f32 ----
  {
    int growb = g0 + wave * 16 + lgrp * 4;
    float impv[4]; int gv[4];
    #pragma unroll
    for (int r = 0; r < 4; ++r) {
      int g = growb + r; gv[r] = g;
      impv[r] = imp[g < G ? g : (G - 1)];
    }
    #pragma unroll
    for (int nf = 0; nf < 8; ++nf) {
      int col = nf * 16 + l15;
      float bmv = bm[col], wlv = wml[col];
      #pragma unroll
      for (int r = 0; r < 4; ++r) {
        float y = acc3[nf][r] + bmv + impv[r] * wlv;
        y = fmaxf(y, 0.f);
        if (gv[r] < G) out[(size_t)gv[r] * 128 + col] = y;
      }
    }
  }
}

extern "C" void kernel_launch(void* const* d_in, const int* in_sizes, int n_in,
                              void* d_out, int out_size, void* d_ws, size_t ws_size,
                              hipStream_t stream) {
  const float* emb = (const float*)d_in[0];
  const int* eg    = (const int*)d_in[1];
  const float* imp = (const float*)d_in[2];
  const float* W1  = (const float*)d_in[3];
  const float* b1  = (const float*)d_in[4];
  const float* g1  = (const float*)d_in[5];
  const float* be1 = (const float*)d_in[6];
  const float* W2  = (const float*)d_in[7];
  const float* b2  = (const float*)d_in[8];
  const float* g2  = (const float*)d_in[9];
  const float* be2 = (const float*)d_in[10];
  const float* Wm  = (const float*)d_in[11];
  const float* bm  = (const float*)d_in[12];
  unsigned short* ws = (unsigned short*)d_ws;
  float* out = (float*)d_out;
  int G = in_sizes[2];

  prep_weights<<<(114816 + 255) / 256, 256, 0, stream>>>(W1, W2, Wm, ws);
  int nblk = (G + 63) / 64;
  fused_edge_group<<<nblk, 256, 0, stream>>>(emb, eg, imp, b1, g1, be1, b2, g2, be2, bm,
                                             ws, out, G);
}